// Round 1
// baseline (213.029 us; speedup 1.0000x reference)
//
#include <hip/hip_runtime.h>
#include <hip/hip_bf16.h>
#include <stdint.h>

typedef unsigned short u16;
typedef __attribute__((ext_vector_type(8))) __bf16 bf16x8;
typedef __attribute__((ext_vector_type(4))) float f32x4;
typedef __attribute__((ext_vector_type(4))) u16 u16x4;
typedef __attribute__((ext_vector_type(4))) float f32x4v;

typedef __attribute__((address_space(1))) void gvoid_t;
typedef __attribute__((address_space(3))) void lvoid_t;

__device__ inline u16 f2bf(float f) {
    uint32_t u = __float_as_uint(f);
    u += 0x7fff + ((u >> 16) & 1);   // RNE
    return (u16)(u >> 16);
}

__device__ inline void gll16(const void* g, void* l) {
    __builtin_amdgcn_global_load_lds((gvoid_t*)g, (lvoid_t*)l, 16, 0, 0);
}

__device__ inline f32x4 mfma16(bf16x8 a, bf16x8 b, f32x4 c) {
    return __builtin_amdgcn_mfma_f32_16x16x32_bf16(a, b, c, 0, 0, 0);
}

// ---------------- cast fp32 -> bf16 (vectorized) ----------------
__global__ __launch_bounds__(256) void cast_bf16_kernel(
        const float* __restrict__ in, u16* __restrict__ out, int n4) {
    int i = blockIdx.x * 256 + threadIdx.x;
    if (i >= n4) return;
    f32x4v f = ((const f32x4v*)in)[i];
    u16x4 o;
    o[0] = f2bf(f[0]); o[1] = f2bf(f[1]); o[2] = f2bf(f[2]); o[3] = f2bf(f[3]);
    ((u16x4*)out)[i] = o;
}

// ---------------- transpose + cast: W[K][N] fp32 -> WT[N][K] bf16 ----------------
__global__ __launch_bounds__(256) void trans_cast_kernel(
        const float* __restrict__ W, u16* __restrict__ WT, int K, int N) {
    __shared__ float t[32][33];
    int x = threadIdx.x;           // 0..31
    int y = threadIdx.y;           // 0..7
    int n0 = blockIdx.x * 32;
    int k0 = blockIdx.y * 32;
    for (int yy = y; yy < 32; yy += 8)
        t[yy][x] = W[(size_t)(k0 + yy) * N + n0 + x];
    __syncthreads();
    for (int yy = y; yy < 32; yy += 8)
        WT[(size_t)(n0 + yy) * K + k0 + x] = f2bf(t[x][yy]);
}

// ---------------- GEMM: C[M][N] = A[M][K] @ Bt[N][K]^T, bf16 MFMA ----------------
// MODE 0: out0 = bf16[(M)][N], value=(acc+bias)*scale       (Q proj, scale=0.125)
// MODE 1: col<1024 -> Kp bf16 [M][1024]; col>=1024 -> VpT bf16 [1024][8192] transposed
// MODE 2: out0 = fp32 [M][N]                                 (O proj -> d_out)
template <int MODE>
__global__ __launch_bounds__(256) void gemm_bt(
        const u16* __restrict__ A, const u16* __restrict__ Bt,
        const float* __restrict__ bias, int M, int N, int K,
        float scale, void* __restrict__ out0, u16* __restrict__ out1) {
    __shared__ u16 lA[2][128 * 32];
    __shared__ u16 lB[2][128 * 32];
    const int tid = threadIdx.x;
    const int lane = tid & 63, wv = tid >> 6;
    const int c16 = lane & 15, g = lane >> 4;
    const int m0 = blockIdx.y * 128, n0 = blockIdx.x * 128;
    const int wm = (wv >> 1) * 64, wn = (wv & 1) * 64;

    // staging: tile = 512 chunks of 16B; chunk i -> row=i>>2, pos=i&3
    // stored-at-pos p holds source chunk c = p ^ ((row>>1)&3)   (bank swizzle)
    const int i0 = tid, i1 = tid + 256;
    const int r0 = i0 >> 2, cc0 = (i0 & 3) ^ ((r0 >> 1) & 3);
    const int r1 = i1 >> 2, cc1 = (i1 & 3) ^ ((r1 >> 1) & 3);
    const int dst0 = (wv * 64) * 8;          // u16 offset, lane*16B added by HW
    const int dst1 = (256 + wv * 64) * 8;

    auto stage = [&](int buf, int k0) {
        gll16(A + (size_t)(m0 + r0) * K + k0 + cc0 * 8, &lA[buf][dst0]);
        gll16(A + (size_t)(m0 + r1) * K + k0 + cc1 * 8, &lA[buf][dst1]);
        gll16(Bt + (size_t)(n0 + r0) * K + k0 + cc0 * 8, &lB[buf][dst0]);
        gll16(Bt + (size_t)(n0 + r1) * K + k0 + cc1 * 8, &lB[buf][dst1]);
    };

    f32x4 acc[4][4] = {};
    stage(0, 0);
    __syncthreads();
    int buf = 0;
    for (int k0 = 0; k0 < K; k0 += 32) {
        if (k0 + 32 < K) stage(buf ^ 1, k0 + 32);
        bf16x8 af[4], bfr[4];
#pragma unroll
        for (int m = 0; m < 4; m++) {
            int row = wm + m * 16 + c16;
            af[m] = *(const bf16x8*)&lA[buf][row * 32 + (g ^ ((row >> 1) & 3)) * 8];
        }
#pragma unroll
        for (int n = 0; n < 4; n++) {
            int row = wn + n * 16 + c16;
            bfr[n] = *(const bf16x8*)&lB[buf][row * 32 + (g ^ ((row >> 1) & 3)) * 8];
        }
#pragma unroll
        for (int m = 0; m < 4; m++)
#pragma unroll
            for (int n = 0; n < 4; n++)
                acc[m][n] = mfma16(af[m], bfr[n], acc[m][n]);
        __syncthreads();
        buf ^= 1;
    }

    // epilogue: C/D layout col=lane&15, row=(lane>>4)*4+reg  [m89]
#pragma unroll
    for (int n = 0; n < 4; n++) {
        int col = n0 + wn + n * 16 + c16;
        float bv = bias[col];
#pragma unroll
        for (int m = 0; m < 4; m++) {
            int rowb = m0 + wm + m * 16 + g * 4;
#pragma unroll
            for (int j = 0; j < 4; j++) {
                float v = (acc[m][n][j] + bv) * scale;
                int row = rowb + j;
                if (MODE == 0) {
                    ((u16*)out0)[(size_t)row * N + col] = f2bf(v);
                } else if (MODE == 1) {
                    if (col < 1024)
                        ((u16*)out0)[(size_t)row * 1024 + col] = f2bf(v);
                    else
                        out1[(size_t)(col - 1024) * 8192 + row] = f2bf(v);
                } else {
                    ((float*)out0)[(size_t)row * N + col] = v;
                }
            }
        }
    }
}

// ---------------- flash attention ----------------
// grid: (qblk=8, h=16, b=4); 4 waves, each 16 q-rows; KV blocks of 64
__global__ __launch_bounds__(256) void attn_kernel(
        const u16* __restrict__ Qp, const u16* __restrict__ Kp,
        const u16* __restrict__ VpT, u16* __restrict__ X) {
    __shared__ u16 lK[2][64 * 64];
    __shared__ u16 lV[2][64 * 64];
    __shared__ u16 lP[4][16][72];   // pad 72 to break b64 bank conflicts
    const int tid = threadIdx.x;
    const int lane = tid & 63, wv = tid >> 6;
    const int c16 = lane & 15, g = lane >> 4;
    const int qblk = blockIdx.x, h = blockIdx.y, b = blockIdx.z;

    // Q fragments in registers (Qp pre-scaled by 1/8)
    const int qrow = b * 512 + qblk * 64 + wv * 16 + c16;
    bf16x8 qf[2];
    qf[0] = *(const bf16x8*)(Qp + (size_t)qrow * 1024 + h * 64 + g * 8);
    qf[1] = *(const bf16x8*)(Qp + (size_t)qrow * 1024 + h * 64 + 32 + g * 8);

    f32x4 acc[4] = {};
    float mrow[4] = {-1e30f, -1e30f, -1e30f, -1e30f};
    float lrow[4] = {0.f, 0.f, 0.f, 0.f};

    // staging: 64x64 bf16 tiles, 8 chunks/row, swizzle pos = c ^ (row&7)
    const int i0 = tid, i1 = tid + 256;
    const int r0 = i0 >> 3, c0 = (i0 & 7) ^ (r0 & 7);
    const int r1 = i1 >> 3, c1 = (i1 & 7) ^ (r1 & 7);
    const int dst0 = (wv * 64) * 8, dst1 = (256 + wv * 64) * 8;

    auto stageKV = [&](int buf, int kv0) {
        gll16(Kp + (size_t)(b * 2048 + kv0 + r0) * 1024 + h * 64 + c0 * 8, &lK[buf][dst0]);
        gll16(Kp + (size_t)(b * 2048 + kv0 + r1) * 1024 + h * 64 + c1 * 8, &lK[buf][dst1]);
        gll16(VpT + (size_t)(h * 64 + r0) * 8192 + b * 2048 + kv0 + c0 * 8, &lV[buf][dst0]);
        gll16(VpT + (size_t)(h * 64 + r1) * 8192 + b * 2048 + kv0 + c1 * 8, &lV[buf][dst1]);
    };

    stageKV(0, 0);
    int buf = 0;
    for (int kv0 = 0; kv0 < 2048; kv0 += 64) {
        __syncthreads();                       // staged tile ready (vmcnt drained)
        if (kv0 + 64 < 2048) stageKV(buf ^ 1, kv0 + 64);

        // S = Q K^T   (S already scaled: Q was pre-multiplied by 1/8)
        f32x4 s[4];
#pragma unroll
        for (int n = 0; n < 4; n++) {
            s[n] = f32x4{0.f, 0.f, 0.f, 0.f};
            int key = n * 16 + c16;
#pragma unroll
            for (int kk = 0; kk < 2; kk++) {
                bf16x8 kf = *(const bf16x8*)&lK[buf][key * 64 + (((kk * 4 + g) ^ (key & 7))) * 8];
                s[n] = mfma16(qf[kk], kf, s[n]);
            }
        }

        // online softmax (rows = g*4+j live in the 16 lanes of group g)
        float p[4][4];
#pragma unroll
        for (int j = 0; j < 4; j++) {
            float v = fmaxf(fmaxf(s[0][j], s[1][j]), fmaxf(s[2][j], s[3][j]));
#pragma unroll
            for (int off = 1; off < 16; off <<= 1) v = fmaxf(v, __shfl_xor(v, off));
            float mn = fmaxf(mrow[j], v);
            float al = __expf(mrow[j] - mn);
            mrow[j] = mn;
            float sum = 0.f;
#pragma unroll
            for (int n = 0; n < 4; n++) { p[n][j] = __expf(s[n][j] - mn); sum += p[n][j]; }
#pragma unroll
            for (int off = 1; off < 16; off <<= 1) sum += __shfl_xor(sum, off);
            lrow[j] = lrow[j] * al + sum;
#pragma unroll
            for (int n = 0; n < 4; n++) acc[n][j] *= al;
        }

        // P -> LDS (wave-private, re-fragment for PV)
#pragma unroll
        for (int j = 0; j < 4; j++)
#pragma unroll
            for (int n = 0; n < 4; n++)
                lP[wv][g * 4 + j][n * 16 + c16] = f2bf(p[n][j]);

        // O += P @ V
#pragma unroll
        for (int kk2 = 0; kk2 < 2; kk2++) {
            union { bf16x8 v8; u16x4 v4[2]; } pu;
            const u16* pp = &lP[wv][c16][kk2 * 32 + g * 8];
            pu.v4[0] = *(const u16x4*)pp;
            pu.v4[1] = *(const u16x4*)(pp + 4);
#pragma unroll
            for (int nd = 0; nd < 4; nd++) {
                int d = nd * 16 + c16;
                bf16x8 vf = *(const bf16x8*)&lV[buf][d * 64 + (((kk2 * 4 + g) ^ (d & 7))) * 8];
                acc[nd] = mfma16(pu.v8, vf, acc[nd]);
            }
        }
        buf ^= 1;
    }

    // write O (bf16) into X[2048][1024]
#pragma unroll
    for (int nd = 0; nd < 4; nd++)
#pragma unroll
        for (int j = 0; j < 4; j++) {
            float o = acc[nd][j] / lrow[j];
            int row = b * 512 + qblk * 64 + wv * 16 + g * 4 + j;
            X[(size_t)row * 1024 + h * 64 + nd * 16 + c16] = f2bf(o);
        }
}

// ---------------- launch ----------------
extern "C" void kernel_launch(void* const* d_in, const int* in_sizes, int n_in,
                              void* d_out, int out_size, void* d_ws, size_t ws_size,
                              hipStream_t stream) {
    const float* queries = (const float*)d_in[0];   // [4,512,1024]
    const float* context = (const float*)d_in[1];   // [4,2048,1024]
    const float* Wq      = (const float*)d_in[2];   // [1024,1024]
    const float* bq      = (const float*)d_in[3];   // [1024]
    const float* Wkv     = (const float*)d_in[4];   // [1024,2048]
    const float* bkv     = (const float*)d_in[5];   // [2048]
    const float* Wo      = (const float*)d_in[6];   // [1024,1024]
    const float* bo      = (const float*)d_in[7];   // [1024]

    char* ws = (char*)d_ws;
    u16* qb   = (u16*)(ws);                         // queries bf16   4MB
    u16* cb   = (u16*)(ws + (4ull  << 20));         // context bf16  16MB
    u16* WqT  = (u16*)(ws + (20ull << 20));         // Wq^T bf16      2MB
    u16* WkvT = (u16*)(ws + (22ull << 20));         // Wkv^T bf16     4MB
    u16* WoT  = (u16*)(ws + (26ull << 20));         // Wo^T bf16      2MB
    u16* Qp   = (u16*)(ws + (28ull << 20));         // q proj (x1/8)  4MB
    u16* Kp   = (u16*)(ws + (32ull << 20));         // k proj        16MB
    u16* VpT  = (u16*)(ws + (48ull << 20));         // v proj ^T     16MB
    u16* X    = (u16*)(ws + (64ull << 20));         // attn out       4MB

    cast_bf16_kernel<<<dim3(2048), dim3(256), 0, stream>>>(queries, qb, 524288);
    cast_bf16_kernel<<<dim3(8192), dim3(256), 0, stream>>>(context, cb, 2097152);
    trans_cast_kernel<<<dim3(32, 32), dim3(32, 8), 0, stream>>>(Wq, WqT, 1024, 1024);
    trans_cast_kernel<<<dim3(64, 32), dim3(32, 8), 0, stream>>>(Wkv, WkvT, 1024, 2048);
    trans_cast_kernel<<<dim3(32, 32), dim3(32, 8), 0, stream>>>(Wo, WoT, 1024, 1024);

    gemm_bt<0><<<dim3(8, 16), dim3(256), 0, stream>>>(qb, WqT, bq, 2048, 1024, 1024,
                                                      0.125f, (void*)Qp, (u16*)nullptr);
    gemm_bt<1><<<dim3(16, 64), dim3(256), 0, stream>>>(cb, WkvT, bkv, 8192, 2048, 1024,
                                                       1.0f, (void*)Kp, VpT);
    attn_kernel<<<dim3(8, 16, 4), dim3(256), 0, stream>>>(Qp, Kp, VpT, X);
    gemm_bt<2><<<dim3(8, 16), dim3(256), 0, stream>>>(X, WoT, bo, 2048, 1024, 1024,
                                                      1.0f, d_out, (u16*)nullptr);
}

// Round 2
// 178.831 us; speedup vs baseline: 1.1912x; 1.1912x over previous
//
#include <hip/hip_runtime.h>
#include <hip/hip_bf16.h>
#include <stdint.h>

typedef unsigned short u16;
typedef __attribute__((ext_vector_type(8))) __bf16 bf16x8;
typedef __attribute__((ext_vector_type(4))) float f32x4;
typedef __attribute__((ext_vector_type(4))) u16 u16x4;
typedef __attribute__((ext_vector_type(4))) float f32x4v;

typedef __attribute__((address_space(1))) void gvoid_t;
typedef __attribute__((address_space(3))) void lvoid_t;

#define BAR()    asm volatile("s_barrier" ::: "memory")
#define WAITV8() asm volatile("s_waitcnt vmcnt(8)" ::: "memory")
#define WAITV4() asm volatile("s_waitcnt vmcnt(4)" ::: "memory")
#define WAITV0() asm volatile("s_waitcnt vmcnt(0)" ::: "memory")

__device__ inline u16 f2bf(float f) {
    uint32_t u = __float_as_uint(f);
    u += 0x7fff + ((u >> 16) & 1);   // RNE
    return (u16)(u >> 16);
}

__device__ inline void gll16(const void* g, void* l) {
    __builtin_amdgcn_global_load_lds((gvoid_t*)g, (lvoid_t*)l, 16, 0, 0);
}

__device__ inline f32x4 mfma16(bf16x8 a, bf16x8 b, f32x4 c) {
    return __builtin_amdgcn_mfma_f32_16x16x32_bf16(a, b, c, 0, 0, 0);
}

// ---------------- cast fp32 -> bf16 (vectorized) ----------------
__global__ __launch_bounds__(256) void cast_bf16_kernel(
        const float* __restrict__ in, u16* __restrict__ out, int n4) {
    int i = blockIdx.x * 256 + threadIdx.x;
    if (i >= n4) return;
    f32x4v f = ((const f32x4v*)in)[i];
    u16x4 o;
    o[0] = f2bf(f[0]); o[1] = f2bf(f[1]); o[2] = f2bf(f[2]); o[3] = f2bf(f[3]);
    ((u16x4*)out)[i] = o;
}

// ---------------- transpose + cast: W[K][N] fp32 -> WT[N][K] bf16 ----------------
__global__ __launch_bounds__(256) void trans_cast_kernel(
        const float* __restrict__ W, u16* __restrict__ WT, int K, int N) {
    __shared__ float t[32][33];
    int x = threadIdx.x;           // 0..31
    int y = threadIdx.y;           // 0..7
    int n0 = blockIdx.x * 32;
    int k0 = blockIdx.y * 32;
    for (int yy = y; yy < 32; yy += 8)
        t[yy][x] = W[(size_t)(k0 + yy) * N + n0 + x];
    __syncthreads();
    for (int yy = y; yy < 32; yy += 8)
        WT[(size_t)(n0 + yy) * K + k0 + x] = f2bf(t[x][yy]);
}

// ---------------- small GEMM (128x128 tile): C = A @ Bt^T ----------------
// MODE 0: out0 = bf16[M][N], value=(acc+bias)*scale     (Q proj, scale=0.125)
// MODE 2: out0 = fp32 [M][N]                            (O proj -> d_out)
template <int MODE>
__global__ __launch_bounds__(256) void gemm_bt(
        const u16* __restrict__ A, const u16* __restrict__ Bt,
        const float* __restrict__ bias, int M, int N, int K,
        float scale, void* __restrict__ out0, u16* __restrict__ out1) {
    __shared__ u16 lA[2][128 * 32];
    __shared__ u16 lB[2][128 * 32];
    const int tid = threadIdx.x;
    const int lane = tid & 63, wv = tid >> 6;
    const int c16 = lane & 15, g = lane >> 4;
    const int m0 = blockIdx.y * 128, n0 = blockIdx.x * 128;
    const int wm = (wv >> 1) * 64, wn = (wv & 1) * 64;

    const int i0 = tid, i1 = tid + 256;
    const int r0 = i0 >> 2, cc0 = (i0 & 3) ^ ((r0 >> 1) & 3);
    const int r1 = i1 >> 2, cc1 = (i1 & 3) ^ ((r1 >> 1) & 3);
    const int dst0 = (wv * 64) * 8;
    const int dst1 = (256 + wv * 64) * 8;

    auto stage = [&](int buf, int k0) {
        gll16(A + (size_t)(m0 + r0) * K + k0 + cc0 * 8, &lA[buf][dst0]);
        gll16(A + (size_t)(m0 + r1) * K + k0 + cc1 * 8, &lA[buf][dst1]);
        gll16(Bt + (size_t)(n0 + r0) * K + k0 + cc0 * 8, &lB[buf][dst0]);
        gll16(Bt + (size_t)(n0 + r1) * K + k0 + cc1 * 8, &lB[buf][dst1]);
    };

    f32x4 acc[4][4] = {};
    stage(0, 0);
    __syncthreads();
    int buf = 0;
    for (int k0 = 0; k0 < K; k0 += 32) {
        if (k0 + 32 < K) stage(buf ^ 1, k0 + 32);
        bf16x8 af[4], bfr[4];
#pragma unroll
        for (int m = 0; m < 4; m++) {
            int row = wm + m * 16 + c16;
            af[m] = *(const bf16x8*)&lA[buf][row * 32 + (g ^ ((row >> 1) & 3)) * 8];
        }
#pragma unroll
        for (int n = 0; n < 4; n++) {
            int row = wn + n * 16 + c16;
            bfr[n] = *(const bf16x8*)&lB[buf][row * 32 + (g ^ ((row >> 1) & 3)) * 8];
        }
#pragma unroll
        for (int m = 0; m < 4; m++)
#pragma unroll
            for (int n = 0; n < 4; n++)
                acc[m][n] = mfma16(af[m], bfr[n], acc[m][n]);
        __syncthreads();
        buf ^= 1;
    }

#pragma unroll
    for (int n = 0; n < 4; n++) {
        int col = n0 + wn + n * 16 + c16;
        float bv = bias[col];
#pragma unroll
        for (int m = 0; m < 4; m++) {
            int rowb = m0 + wm + m * 16 + g * 4;
#pragma unroll
            for (int j = 0; j < 4; j++) {
                float v = (acc[m][n][j] + bv) * scale;
                int row = rowb + j;
                if (MODE == 0) {
                    ((u16*)out0)[(size_t)row * N + col] = f2bf(v);
                } else {
                    ((float*)out0)[(size_t)row * N + col] = v;
                }
            }
        }
    }
}

// ---------------- big GEMM: 256x256 tile, 8 waves, 4-deep ring, counted vmcnt ----
// KV projection: C[M=8192][N=2048] = A[M][K=1024] @ Bt[N][K]^T + bias
// cols < 1024 -> Kp bf16 [M][1024] ; cols >= 1024 -> VpT bf16 [1024][8192]
// Per block: M-tile 256, N-tile 256, BK=32. 4 ring slots x (A 16KB + B 16KB) = 128KB LDS.
// Per tile per wave: 4 global_load_lds (prefetch t+3), 12 ds_read_b128, 32 MFMA.
// s_waitcnt vmcnt(8): tiles t+1,t+2 (8 loads/wave) stay in flight across barriers (T4).
__global__ __launch_bounds__(512, 2) void gemm_kv_ring(
        const u16* __restrict__ A, const u16* __restrict__ Bt,
        const float* __restrict__ bias, u16* __restrict__ Kp,
        u16* __restrict__ VpT) {
    __shared__ u16 lds[4][2][256 * 32];   // [slot][A=0/B=1][row*32 + swz-chunk*8]
    const int K = 1024, NT = 32;          // K / 32
    const int tid = threadIdx.x;
    const int lane = tid & 63, wv = tid >> 6;
    const int c16 = lane & 15, g = lane >> 4;

    // T1: XCD-aware swizzle (grid 8x32=256, %8==0 -> simple bijective form)
    const int nwg = gridDim.x * gridDim.y;
    const int bid = blockIdx.y * gridDim.x + blockIdx.x;
    const int cpx = nwg >> 3;
    const int sw = (bid & 7) * cpx + (bid >> 3);
    const int bx = sw % gridDim.x, by = sw / gridDim.x;
    const int m0 = by * 256, n0 = bx * 256;

    // staging: waves 0-3 stage A rows wv*64..+63, waves 4-7 stage B rows (wv-4)*64..+63
    const int isB = wv >> 2;
    const int rbase = (wv & 3) * 64;
    const u16* src = isB ? Bt : A;
    const int base0 = isB ? n0 : m0;
    size_t off[4];
    const u16* ldst[4];
#pragma unroll
    for (int i = 0; i < 4; i++) {
        int rl = rbase + i * 16 + (lane >> 2);              // local row this lane loads
        int ch = (lane & 3) ^ ((rl >> 1) & 3);              // pre-swizzled source chunk
        off[i] = (size_t)(base0 + rl) * K + ch * 8;
        ldst[i] = &lds[0][0][0] + ((size_t)isB * 256 * 32) + (size_t)(rbase + i * 16) * 32;
    }
    const size_t slotStride = 2 * 256 * 32;                 // u16 elements per slot

    auto stage = [&](int t) {
        const u16* s0 = src + (size_t)t * 32;               // k0 = t*32
        u16* d = (u16*)ldst[0] + (size_t)(t & 3) * slotStride;
        gll16(s0 + off[0], d);
        gll16(s0 + off[1], d + 16 * 32);
        gll16(s0 + off[2], d + 32 * 32);
        gll16(s0 + off[3], d + 48 * 32);
    };

    const int wm = wv >> 2;        // 0..1 -> 128-row half
    const int wn = wv & 3;         // 0..3 -> 64-col quarter
    f32x4 acc[8][4] = {};

    auto compute = [&](int slot) {
        const u16* la = &lds[slot][0][0];
        const u16* lb = &lds[slot][1][0];
        bf16x8 af[8], bfr[4];
#pragma unroll
        for (int m = 0; m < 8; m++) {
            int row = wm * 128 + m * 16 + c16;
            af[m] = *(const bf16x8*)&la[row * 32 + (g ^ ((row >> 1) & 3)) * 8];
        }
#pragma unroll
        for (int n = 0; n < 4; n++) {
            int row = wn * 64 + n * 16 + c16;
            bfr[n] = *(const bf16x8*)&lb[row * 32 + (g ^ ((row >> 1) & 3)) * 8];
        }
#pragma unroll
        for (int m = 0; m < 8; m++)
#pragma unroll
            for (int n = 0; n < 4; n++)
                acc[m][n] = mfma16(af[m], bfr[n], acc[m][n]);
    };

    // prologue: tiles 0,1,2 -> slots 0,1,2 (12 loads/wave in flight)
    stage(0); stage(1); stage(2);

    for (int t = 0; t < NT - 2; ++t) {
        WAITV8();                          // tile t landed; t+1,t+2 in flight
        BAR();
        if (t + 3 < NT) stage(t + 3);      // slot (t+3)&3, freed by barrier
        compute(t & 3);
    }
    WAITV4(); BAR(); compute((NT - 2) & 3);
    WAITV0(); BAR(); compute((NT - 1) & 3);

    // epilogue: whole block is K-part (n0<1024) or V-part (n0>=1024)
    const bool isV = (n0 >= 1024);
#pragma unroll
    for (int n = 0; n < 4; n++) {
        int col = n0 + wn * 64 + n * 16 + c16;
        float bv = bias[col];
#pragma unroll
        for (int m = 0; m < 8; m++) {
            int rowb = m0 + wm * 128 + m * 16 + g * 4;
            if (isV) {
                u16x4 pk;                   // j = consecutive kv rows -> one 8B store
#pragma unroll
                for (int j = 0; j < 4; j++) pk[j] = f2bf(acc[m][n][j] + bv);
                *(u16x4*)&VpT[(size_t)(col - 1024) * 8192 + rowb] = pk;
            } else {
#pragma unroll
                for (int j = 0; j < 4; j++)
                    Kp[(size_t)(rowb + j) * 1024 + col] = f2bf(acc[m][n][j] + bv);
            }
        }
    }
}

// ---------------- flash attention ----------------
// grid: (qblk=8, h=16, b=4); 4 waves, each 16 q-rows; KV blocks of 64
__global__ __launch_bounds__(256) void attn_kernel(
        const u16* __restrict__ Qp, const u16* __restrict__ Kp,
        const u16* __restrict__ VpT, u16* __restrict__ X) {
    __shared__ u16 lK[2][64 * 64];
    __shared__ u16 lV[2][64 * 64];
    __shared__ u16 lP[4][16][72];
    const int tid = threadIdx.x;
    const int lane = tid & 63, wv = tid >> 6;
    const int c16 = lane & 15, g = lane >> 4;
    const int qblk = blockIdx.x, h = blockIdx.y, b = blockIdx.z;

    const int qrow = b * 512 + qblk * 64 + wv * 16 + c16;
    bf16x8 qf[2];
    qf[0] = *(const bf16x8*)(Qp + (size_t)qrow * 1024 + h * 64 + g * 8);
    qf[1] = *(const bf16x8*)(Qp + (size_t)qrow * 1024 + h * 64 + 32 + g * 8);

    f32x4 acc[4] = {};
    float mrow[4] = {-1e30f, -1e30f, -1e30f, -1e30f};
    float lrow[4] = {0.f, 0.f, 0.f, 0.f};

    const int i0 = tid, i1 = tid + 256;
    const int r0 = i0 >> 3, c0 = (i0 & 7) ^ (r0 & 7);
    const int r1 = i1 >> 3, c1 = (i1 & 7) ^ (r1 & 7);
    const int dst0 = (wv * 64) * 8, dst1 = (256 + wv * 64) * 8;

    auto stageKV = [&](int buf, int kv0) {
        gll16(Kp + (size_t)(b * 2048 + kv0 + r0) * 1024 + h * 64 + c0 * 8, &lK[buf][dst0]);
        gll16(Kp + (size_t)(b * 2048 + kv0 + r1) * 1024 + h * 64 + c1 * 8, &lK[buf][dst1]);
        gll16(VpT + (size_t)(h * 64 + r0) * 8192 + b * 2048 + kv0 + c0 * 8, &lV[buf][dst0]);
        gll16(VpT + (size_t)(h * 64 + r1) * 8192 + b * 2048 + kv0 + c1 * 8, &lV[buf][dst1]);
    };

    stageKV(0, 0);
    int buf = 0;
    for (int kv0 = 0; kv0 < 2048; kv0 += 64) {
        __syncthreads();
        if (kv0 + 64 < 2048) stageKV(buf ^ 1, kv0 + 64);

        f32x4 s[4];
#pragma unroll
        for (int n = 0; n < 4; n++) {
            s[n] = f32x4{0.f, 0.f, 0.f, 0.f};
            int key = n * 16 + c16;
#pragma unroll
            for (int kk = 0; kk < 2; kk++) {
                bf16x8 kf = *(const bf16x8*)&lK[buf][key * 64 + (((kk * 4 + g) ^ (key & 7))) * 8];
                s[n] = mfma16(qf[kk], kf, s[n]);
            }
        }

        float p[4][4];
#pragma unroll
        for (int j = 0; j < 4; j++) {
            float v = fmaxf(fmaxf(s[0][j], s[1][j]), fmaxf(s[2][j], s[3][j]));
#pragma unroll
            for (int off = 1; off < 16; off <<= 1) v = fmaxf(v, __shfl_xor(v, off));
            float mn = fmaxf(mrow[j], v);
            float al = __expf(mrow[j] - mn);
            mrow[j] = mn;
            float sum = 0.f;
#pragma unroll
            for (int n = 0; n < 4; n++) { p[n][j] = __expf(s[n][j] - mn); sum += p[n][j]; }
#pragma unroll
            for (int off = 1; off < 16; off <<= 1) sum += __shfl_xor(sum, off);
            lrow[j] = lrow[j] * al + sum;
#pragma unroll
            for (int n = 0; n < 4; n++) acc[n][j] *= al;
        }

#pragma unroll
        for (int j = 0; j < 4; j++)
#pragma unroll
            for (int n = 0; n < 4; n++)
                lP[wv][g * 4 + j][n * 16 + c16] = f2bf(p[n][j]);

#pragma unroll
        for (int kk2 = 0; kk2 < 2; kk2++) {
            union { bf16x8 v8; u16x4 v4[2]; } pu;
            const u16* pp = &lP[wv][c16][kk2 * 32 + g * 8];
            pu.v4[0] = *(const u16x4*)pp;
            pu.v4[1] = *(const u16x4*)(pp + 4);
#pragma unroll
            for (int nd = 0; nd < 4; nd++) {
                int d = nd * 16 + c16;
                bf16x8 vf = *(const bf16x8*)&lV[buf][d * 64 + (((kk2 * 4 + g) ^ (d & 7))) * 8];
                acc[nd] = mfma16(pu.v8, vf, acc[nd]);
            }
        }
        buf ^= 1;
    }

#pragma unroll
    for (int nd = 0; nd < 4; nd++)
#pragma unroll
        for (int j = 0; j < 4; j++) {
            float o = acc[nd][j] / lrow[j];
            int row = b * 512 + qblk * 64 + wv * 16 + g * 4 + j;
            X[(size_t)row * 1024 + h * 64 + nd * 16 + c16] = f2bf(o);
        }
}

// ---------------- launch ----------------
extern "C" void kernel_launch(void* const* d_in, const int* in_sizes, int n_in,
                              void* d_out, int out_size, void* d_ws, size_t ws_size,
                              hipStream_t stream) {
    const float* queries = (const float*)d_in[0];   // [4,512,1024]
    const float* context = (const float*)d_in[1];   // [4,2048,1024]
    const float* Wq      = (const float*)d_in[2];   // [1024,1024]
    const float* bq      = (const float*)d_in[3];   // [1024]
    const float* Wkv     = (const float*)d_in[4];   // [1024,2048]
    const float* bkv     = (const float*)d_in[5];   // [2048]
    const float* Wo      = (const float*)d_in[6];   // [1024,1024]
    const float* bo      = (const float*)d_in[7];   // [1024]

    char* ws = (char*)d_ws;
    u16* qb   = (u16*)(ws);                         // queries bf16   4MB
    u16* cb   = (u16*)(ws + (4ull  << 20));         // context bf16  16MB
    u16* WqT  = (u16*)(ws + (20ull << 20));         // Wq^T bf16      2MB
    u16* WkvT = (u16*)(ws + (22ull << 20));         // Wkv^T bf16     4MB
    u16* WoT  = (u16*)(ws + (26ull << 20));         // Wo^T bf16      2MB
    u16* Qp   = (u16*)(ws + (28ull << 20));         // q proj (x1/8)  4MB
    u16* Kp   = (u16*)(ws + (32ull << 20));         // k proj        16MB
    u16* VpT  = (u16*)(ws + (48ull << 20));         // v proj ^T     16MB
    u16* X    = (u16*)(ws + (64ull << 20));         // attn out       4MB

    cast_bf16_kernel<<<dim3(2048), dim3(256), 0, stream>>>(queries, qb, 524288);
    cast_bf16_kernel<<<dim3(8192), dim3(256), 0, stream>>>(context, cb, 2097152);
    trans_cast_kernel<<<dim3(32, 32), dim3(32, 8), 0, stream>>>(Wq, WqT, 1024, 1024);
    trans_cast_kernel<<<dim3(64, 32), dim3(32, 8), 0, stream>>>(Wkv, WkvT, 1024, 2048);
    trans_cast_kernel<<<dim3(32, 32), dim3(32, 8), 0, stream>>>(Wo, WoT, 1024, 1024);

    gemm_bt<0><<<dim3(8, 16), dim3(256), 0, stream>>>(qb, WqT, bq, 2048, 1024, 1024,
                                                      0.125f, (void*)Qp, (u16*)nullptr);
    gemm_kv_ring<<<dim3(8, 32), dim3(512), 0, stream>>>(cb, WkvT, bkv, Kp, VpT);
    attn_kernel<<<dim3(8, 16, 4), dim3(256), 0, stream>>>(Qp, Kp, VpT, X);
    gemm_bt<2><<<dim3(8, 16), dim3(256), 0, stream>>>(X, WoT, bo, 2048, 1024, 1024,
                                                      1.0f, d_out, (u16*)nullptr);
}